// Round 1
// baseline (637.478 us; speedup 1.0000x reference)
//
#include <hip/hip_runtime.h>
#include <cstdint>

#define BB 32
#define NATOM 256
#define NN 100
#define NF 42
#define HH 50
#define PADROWS 257                    // 1 + NATOM
#define DE_STRIDE (PADROWS * NF)       // 10794 floats per batch

// ---------------------------------------------------------------------------
// Kernel 1: per-atom MLP forward (Ei, Etot) + analytic input gradient dE/dx.
// grid = 64 blocks (b = blk>>1, half = blk&1 selects atom-type / param set),
// block = 128 threads, one thread per atom. Weights staged in LDS; all lanes
// read the same LDS address in the inner loops -> broadcast, conflict-free.
// ---------------------------------------------------------------------------
__global__ __launch_bounds__(128) void mlp_fwd_bwd(
    const float* __restrict__ image,
    const float* __restrict__ W0a, const float* __restrict__ b0a,
    const float* __restrict__ W1a, const float* __restrict__ b1a,
    const float* __restrict__ W2a, const float* __restrict__ b2a,
    const float* __restrict__ W0b, const float* __restrict__ b0b,
    const float* __restrict__ W1b, const float* __restrict__ b1b,
    const float* __restrict__ W2b, const float* __restrict__ b2b,
    float* __restrict__ outEtot,   // [32]
    float* __restrict__ outEi,     // [32*256]
    float* __restrict__ dEp)       // [32 * 257 * 42] (row 0 per batch = zeros)
{
    __shared__ float W0s[NF * HH];
    __shared__ float W1s[HH * HH];
    __shared__ float W2s[HH], b0s[HH], b1s[HH];
    __shared__ float b2s;
    __shared__ float red[128];

    const int blk  = blockIdx.x;
    const int b    = blk >> 1;
    const int half = blk & 1;
    const int tid  = threadIdx.x;

    const float* W0 = half ? W0b : W0a;
    const float* b0 = half ? b0b : b0a;
    const float* W1 = half ? W1b : W1a;
    const float* b1 = half ? b1b : b1a;
    const float* W2 = half ? W2b : W2a;
    const float* b2 = half ? b2b : b2a;

    for (int i = tid; i < NF * HH; i += 128) W0s[i] = W0[i];
    for (int i = tid; i < HH * HH; i += 128) W1s[i] = W1[i];
    if (tid < HH) { W2s[tid] = W2[tid]; b0s[tid] = b0[tid]; b1s[tid] = b1[tid]; }
    if (tid == 0) b2s = b2[0];

    // zero pad-row (dE_pad[b][0][:]) once per batch
    if (half == 0 && tid < NF) dEp[(size_t)b * DE_STRIDE + tid] = 0.0f;
    __syncthreads();

    const int n = half * 128 + tid;          // atom within batch
    const int g = b * NATOM + n;             // global atom

    float x[NF];
    {
        const float* xp = image + (size_t)g * NF;
        #pragma unroll
        for (int f = 0; f < NF; ++f) x[f] = xp[f];
    }

    float h0[HH], h1[HH];

    // layer 0: h0 = tanh(x @ W0 + b0), 2-way j-unroll for ILP
    for (int j = 0; j < HH; j += 2) {
        float s0 = b0s[j], s1 = b0s[j + 1];
        #pragma unroll
        for (int f = 0; f < NF; ++f) {
            const float xf = x[f];
            s0 += xf * W0s[f * HH + j];
            s1 += xf * W0s[f * HH + j + 1];
        }
        h0[j] = tanhf(s0);
        h0[j + 1] = tanhf(s1);
    }

    // layer 1: h1 = tanh(h0 @ W1 + b1)
    for (int j = 0; j < HH; j += 2) {
        float s0 = b1s[j], s1 = b1s[j + 1];
        #pragma unroll
        for (int i = 0; i < HH; ++i) {
            const float hi = h0[i];
            s0 += hi * W1s[i * HH + j];
            s1 += hi * W1s[i * HH + j + 1];
        }
        h1[j] = tanhf(s0);
        h1[j + 1] = tanhf(s1);
    }

    // output: Ei = h1 @ W2 + b2
    float Ei0 = 0.0f, Ei1 = 0.0f;
    for (int j = 0; j < HH; j += 2) {
        Ei0 += h1[j] * W2s[j];
        Ei1 += h1[j + 1] * W2s[j + 1];
    }
    const float Ei = Ei0 + Ei1 + b2s;
    outEi[g] = Ei;

    // Etot: block reduce + one atomic per block
    red[tid] = Ei;
    __syncthreads();
    for (int o = 64; o > 0; o >>= 1) {
        if (tid < o) red[tid] += red[tid + o];
        __syncthreads();
    }
    if (tid == 0) atomicAdd(&outEtot[b], red[0]);

    // ---- backward: dEi/dx = W0 diag(1-h0^2) W1 diag(1-h1^2) W2 ----
    // g1 = W2 * (1 - h1^2)   (overwrite h1)
    #pragma unroll
    for (int j = 0; j < HH; ++j) {
        const float t = h1[j];
        h1[j] = W2s[j] * (1.0f - t * t);
    }
    // g0 = (W1 @ g1) * (1 - h0^2)  (overwrite h0)
    for (int i = 0; i < HH; i += 2) {
        float s0 = 0.0f, s1 = 0.0f;
        #pragma unroll
        for (int j = 0; j < HH; ++j) {
            const float gj = h1[j];
            s0 += gj * W1s[i * HH + j];
            s1 += gj * W1s[(i + 1) * HH + j];
        }
        const float t0 = h0[i], t1 = h0[i + 1];
        h0[i] = s0 * (1.0f - t0 * t0);
        h0[i + 1] = s1 * (1.0f - t1 * t1);
    }
    // dx = W0 @ g0
    float* dxp = dEp + (size_t)b * DE_STRIDE + (size_t)(1 + n) * NF;
    for (int f = 0; f < NF; f += 2) {
        float s0 = 0.0f, s1 = 0.0f;
        #pragma unroll
        for (int i = 0; i < HH; ++i) {
            const float gi = h0[i];
            s0 += gi * W0s[f * HH + i];
            s1 += gi * W0s[(f + 1) * HH + i];
        }
        dxp[f] = s0;
        dxp[f + 1] = s1;
    }
}

// ---------------------------------------------------------------------------
// Kernel 2: Force[b,n,d] = sum_{k,f} dE_pad[b, nbr[b,n,k], f] * dfeat[b,n,k,f,d]
// One block (256 thr = 4 waves) per (b,n). dfeat streamed with aligned float4:
// each wave owns one 252-float chunk-pair (2 k's) per iteration, so each
// lane's (k_off, f, d) decomposition of its 4 components is loop-invariant.
// ---------------------------------------------------------------------------
__global__ __launch_bounds__(256) void force_kernel(
    const float* __restrict__ dfeat,     // [32*256*100*42*3]
    const int* __restrict__ neighbor,    // [32*256*100]
    const float* __restrict__ dEp,       // [32 * 257 * 42]
    float* __restrict__ outForce)        // [32*256*3]
{
    __shared__ int   nbr_s[NN];
    __shared__ float dE_s[NN * NF];      // 16.8 KB
    __shared__ float red[3 * 256];

    const int bn  = blockIdx.x;          // b*256 + n
    const int b   = bn >> 8;
    const int tid = threadIdx.x;

    if (tid < NN) nbr_s[tid] = neighbor[(size_t)bn * NN + tid];
    __syncthreads();

    // gather the 100 needed dE rows into LDS (hits L1/L2: 43 KB per batch)
    {
        const float* dEb = dEp + (size_t)b * DE_STRIDE;
        for (int q = tid; q < NN * NF; q += 256) {
            const int k = q / NF;
            const int f = q - k * NF;
            dE_s[q] = dEb[nbr_s[k] * NF + f];
        }
    }
    __syncthreads();

    const int w = tid >> 6;              // wave 0..3
    const int l = tid & 63;              // lane

    // components r = 4l..4l+3 within a 252-float chunk-pair (valid if l<63)
    int off0 = 0, off1 = 0, off2 = 0, off3 = 0;
    int d0 = 0, d1 = 0, d2 = 0, d3 = 0;
    float acc0 = 0.0f, acc1 = 0.0f, acc2 = 0.0f, acc3 = 0.0f;
    const bool active = (l < 63);
    if (active) {
        const int r = 4 * l;
        #define DECOMP(c, OFF, DD) { int rc = r + (c); int ko = (rc >= 126) ? 1 : 0; \
            int rr = rc - 126 * ko; int f = rr / 3; (DD) = rr - 3 * f; (OFF) = ko * NF + f; }
        DECOMP(0, off0, d0) DECOMP(1, off1, d1) DECOMP(2, off2, d2) DECOMP(3, off3, d3)
        #undef DECOMP

        const float4* df4 = (const float4*)dfeat + (size_t)bn * 3150;
        for (int p = w; p < 50; p += 4) {   // chunk-pair index
            const float4 v = df4[p * 63 + l];
            const float* base = dE_s + 84 * p;
            acc0 += v.x * base[off0];
            acc1 += v.y * base[off1];
            acc2 += v.z * base[off2];
            acc3 += v.w * base[off3];
        }
    }

    // merge 4 per-lane accumulators into 3 components (branchless)
    const float s0 = (d0 == 0 ? acc0 : 0.0f) + (d1 == 0 ? acc1 : 0.0f) +
                     (d2 == 0 ? acc2 : 0.0f) + (d3 == 0 ? acc3 : 0.0f);
    const float s1 = (d0 == 1 ? acc0 : 0.0f) + (d1 == 1 ? acc1 : 0.0f) +
                     (d2 == 1 ? acc2 : 0.0f) + (d3 == 1 ? acc3 : 0.0f);
    const float s2 = (d0 == 2 ? acc0 : 0.0f) + (d1 == 2 ? acc1 : 0.0f) +
                     (d2 == 2 ? acc2 : 0.0f) + (d3 == 2 ? acc3 : 0.0f);

    red[tid] = s0; red[256 + tid] = s1; red[512 + tid] = s2;
    __syncthreads();
    for (int o = 128; o > 0; o >>= 1) {
        if (tid < o) {
            red[tid]       += red[tid + o];
            red[256 + tid] += red[256 + tid + o];
            red[512 + tid] += red[512 + tid + o];
        }
        __syncthreads();
    }
    if (tid < 3) outForce[(size_t)bn * 3 + tid] = red[tid * 256];
}

extern "C" void kernel_launch(void* const* d_in, const int* in_sizes, int n_in,
                              void* d_out, int out_size, void* d_ws, size_t ws_size,
                              hipStream_t stream) {
    const float* image    = (const float*)d_in[0];
    const float* dfeat    = (const float*)d_in[1];
    const int*   neighbor = (const int*)d_in[2];
    const float* W0_t0 = (const float*)d_in[3];
    const float* b0_t0 = (const float*)d_in[4];
    const float* W1_t0 = (const float*)d_in[5];
    const float* b1_t0 = (const float*)d_in[6];
    const float* W2_t0 = (const float*)d_in[7];
    const float* b2_t0 = (const float*)d_in[8];
    const float* W0_t1 = (const float*)d_in[9];
    const float* b0_t1 = (const float*)d_in[10];
    const float* W1_t1 = (const float*)d_in[11];
    const float* b1_t1 = (const float*)d_in[12];
    const float* W2_t1 = (const float*)d_in[13];
    const float* b2_t1 = (const float*)d_in[14];

    float* outEtot  = (float*)d_out;          // 32
    float* outEi    = outEtot + BB;           // 32*256 = 8192
    float* outForce = outEi + BB * NATOM;     // 32*256*3 = 24576
    float* dEp      = (float*)d_ws;           // 32*257*42 floats = 1.38 MB

    // Etot is accumulated with atomics -> zero its region every call
    hipMemsetAsync(d_out, 0, BB * sizeof(float), stream);

    mlp_fwd_bwd<<<64, 128, 0, stream>>>(
        image,
        W0_t0, b0_t0, W1_t0, b1_t0, W2_t0, b2_t0,
        W0_t1, b0_t1, W1_t1, b1_t1, W2_t1, b2_t1,
        outEtot, outEi, dEp);

    force_kernel<<<BB * NATOM, 256, 0, stream>>>(dfeat, neighbor, dEp, outForce);
}

// Round 2
// 625.385 us; speedup vs baseline: 1.0193x; 1.0193x over previous
//
#include <hip/hip_runtime.h>
#include <cstdint>

#define BB 32
#define NATOM 256
#define NN 100
#define NF 42
#define HH 50
#define PADROWS 257                    // 1 + NATOM
#define DE_STRIDE (PADROWS * NF)       // 10794 floats per batch

// fast tanh: 1 - 2/(e^{2x}+1).  Saturates correctly at +/-1 (e->0 or inf).
// Uses v_exp_f32 via __expf; ~1e-6 rel err, far under the 20.48 absmax budget.
__device__ __forceinline__ float fast_tanh(float x) {
    const float e = __expf(2.0f * x);
    return 1.0f - 2.0f / (e + 1.0f);
}

// ---------------------------------------------------------------------------
// Kernel 1: per-atom MLP forward (Ei, Etot) + analytic input gradient dE/dx.
// grid = 64 blocks (b = blk>>1, half = blk&1 selects atom-type / param set),
// block = 128 threads, one thread per atom. Weights staged in LDS; all lanes
// read the same LDS address in the inner loops -> broadcast, conflict-free.
// ---------------------------------------------------------------------------
__global__ __launch_bounds__(128) void mlp_fwd_bwd(
    const float* __restrict__ image,
    const float* __restrict__ W0a, const float* __restrict__ b0a,
    const float* __restrict__ W1a, const float* __restrict__ b1a,
    const float* __restrict__ W2a, const float* __restrict__ b2a,
    const float* __restrict__ W0b, const float* __restrict__ b0b,
    const float* __restrict__ W1b, const float* __restrict__ b1b,
    const float* __restrict__ W2b, const float* __restrict__ b2b,
    float* __restrict__ outEtot,   // [32]
    float* __restrict__ outEi,     // [32*256]
    float* __restrict__ dEp)       // [32 * 257 * 42] (row 0 per batch = zeros)
{
    __shared__ float W0s[NF * HH];
    __shared__ float W1s[HH * HH];
    __shared__ float W2s[HH], b0s[HH], b1s[HH];
    __shared__ float b2s;
    __shared__ float red[128];

    const int blk  = blockIdx.x;
    const int b    = blk >> 1;
    const int half = blk & 1;
    const int tid  = threadIdx.x;

    const float* W0 = half ? W0b : W0a;
    const float* b0 = half ? b0b : b0a;
    const float* W1 = half ? W1b : W1a;
    const float* b1 = half ? b1b : b1a;
    const float* W2 = half ? W2b : W2a;
    const float* b2 = half ? b2b : b2a;

    for (int i = tid; i < NF * HH; i += 128) W0s[i] = W0[i];
    for (int i = tid; i < HH * HH; i += 128) W1s[i] = W1[i];
    if (tid < HH) { W2s[tid] = W2[tid]; b0s[tid] = b0[tid]; b1s[tid] = b1[tid]; }
    if (tid == 0) b2s = b2[0];

    // zero pad-row (dE_pad[b][0][:]) once per batch
    if (half == 0 && tid < NF) dEp[(size_t)b * DE_STRIDE + tid] = 0.0f;
    __syncthreads();

    const int n = half * 128 + tid;          // atom within batch
    const int g = b * NATOM + n;             // global atom

    float x[NF];
    {
        // row is 168 B (8-aligned) -> 21 aligned float2 loads
        const float2* xp = (const float2*)(image + (size_t)g * NF);
        #pragma unroll
        for (int f = 0; f < NF / 2; ++f) {
            const float2 v = xp[f];
            x[2 * f] = v.x;
            x[2 * f + 1] = v.y;
        }
    }

    float h0[HH], h1[HH];

    // layer 0: h0 = tanh(x @ W0 + b0), 2-way j-unroll for ILP
    for (int j = 0; j < HH; j += 2) {
        float s0 = b0s[j], s1 = b0s[j + 1];
        #pragma unroll
        for (int f = 0; f < NF; ++f) {
            const float xf = x[f];
            s0 += xf * W0s[f * HH + j];
            s1 += xf * W0s[f * HH + j + 1];
        }
        h0[j] = fast_tanh(s0);
        h0[j + 1] = fast_tanh(s1);
    }

    // layer 1: h1 = tanh(h0 @ W1 + b1)
    for (int j = 0; j < HH; j += 2) {
        float s0 = b1s[j], s1 = b1s[j + 1];
        #pragma unroll
        for (int i = 0; i < HH; ++i) {
            const float hi = h0[i];
            s0 += hi * W1s[i * HH + j];
            s1 += hi * W1s[i * HH + j + 1];
        }
        h1[j] = fast_tanh(s0);
        h1[j + 1] = fast_tanh(s1);
    }

    // output: Ei = h1 @ W2 + b2
    float Ei0 = 0.0f, Ei1 = 0.0f;
    for (int j = 0; j < HH; j += 2) {
        Ei0 += h1[j] * W2s[j];
        Ei1 += h1[j + 1] * W2s[j + 1];
    }
    const float Ei = Ei0 + Ei1 + b2s;
    outEi[g] = Ei;

    // Etot: block reduce + one atomic per block
    red[tid] = Ei;
    __syncthreads();
    for (int o = 64; o > 0; o >>= 1) {
        if (tid < o) red[tid] += red[tid + o];
        __syncthreads();
    }
    if (tid == 0) atomicAdd(&outEtot[b], red[0]);

    // ---- backward: dEi/dx = W0 diag(1-h0^2) W1 diag(1-h1^2) W2 ----
    // g1 = W2 * (1 - h1^2)   (overwrite h1)
    #pragma unroll
    for (int j = 0; j < HH; ++j) {
        const float t = h1[j];
        h1[j] = W2s[j] * (1.0f - t * t);
    }
    // g0 = (W1 @ g1) * (1 - h0^2)  (overwrite h0)
    for (int i = 0; i < HH; i += 2) {
        float s0 = 0.0f, s1 = 0.0f;
        #pragma unroll
        for (int j = 0; j < HH; ++j) {
            const float gj = h1[j];
            s0 += gj * W1s[i * HH + j];
            s1 += gj * W1s[(i + 1) * HH + j];
        }
        const float t0 = h0[i], t1 = h0[i + 1];
        h0[i] = s0 * (1.0f - t0 * t0);
        h0[i + 1] = s1 * (1.0f - t1 * t1);
    }
    // dx = W0 @ g0   (168-B rows, 8-aligned -> float2 stores)
    float2* dxp = (float2*)(dEp + (size_t)b * DE_STRIDE + (size_t)(1 + n) * NF);
    for (int f = 0; f < NF; f += 2) {
        float s0 = 0.0f, s1 = 0.0f;
        #pragma unroll
        for (int i = 0; i < HH; ++i) {
            const float gi = h0[i];
            s0 += gi * W0s[f * HH + i];
            s1 += gi * W0s[(f + 1) * HH + i];
        }
        dxp[f >> 1] = make_float2(s0, s1);
    }
}

// ---------------------------------------------------------------------------
// Kernel 2: Force[b,n,d] = sum_{k,f} dE_pad[b, nbr[b,n,k], f] * dfeat[b,n,k,f,d]
// One block (256 thr = 4 waves) per (b,n).
//  - All per-wave dfeat float4 loads are ISSUED FIRST (registers), so they are
//    in flight while the block loads neighbors + gathers dE rows into LDS.
//  - Each wave owns a CONTIGUOUS range of 252-float chunk-pairs (2 k's each),
//    so each lane's (k_off,f,d) decomposition of its 4 components is fixed.
//  - Wave-level __shfl_xor reduction replaces the 8-round LDS tree.
// ---------------------------------------------------------------------------
__global__ __launch_bounds__(256) void force_kernel(
    const float* __restrict__ dfeat,     // [32*256*100*42*3]
    const int* __restrict__ neighbor,    // [32*256*100]
    const float* __restrict__ dEp,       // [32 * 257 * 42]
    float* __restrict__ outForce)        // [32*256*3]
{
    __shared__ int   nbr_s[NN];
    __shared__ float dE_s[NN * NF];      // 16.8 KB
    __shared__ float part[4][3];

    const int bn  = blockIdx.x;          // b*256 + n
    const int b   = bn >> 8;
    const int tid = threadIdx.x;
    const int w   = tid >> 6;            // wave 0..3
    const int l   = tid & 63;            // lane

    // wave w owns chunk-pairs [start, start+cnt): 13,13,12,12
    const int start = (w < 2) ? 13 * w : 26 + 12 * (w - 2);
    const int cnt   = (w < 2) ? 13 : 12;

    // ---- phase 0: issue all dfeat loads (63 active lanes x up to 13 float4)
    float4 v[13];
    const float4* df4 = (const float4*)dfeat + (size_t)bn * 3150;
    if (l < 63) {
        #pragma unroll
        for (int i = 0; i < 13; ++i) {
            int p = start + i;
            if (p > 49) p = 49;          // clamp (w>=2, i==12): valid addr, zeroed below
            v[i] = df4[p * 63 + l];
        }
        if (w >= 2) v[12] = make_float4(0.0f, 0.0f, 0.0f, 0.0f);
    }

    // ---- phase 1: neighbors + dE gather into LDS (overlaps dfeat latency)
    if (tid < NN) nbr_s[tid] = neighbor[(size_t)bn * NN + tid];
    __syncthreads();
    {
        const float* dEb = dEp + (size_t)b * DE_STRIDE;
        for (int q = tid; q < NN * NF; q += 256) {
            const int k = q / NF;
            const int f = q - k * NF;
            dE_s[q] = dEb[nbr_s[k] * NF + f];
        }
    }
    __syncthreads();

    // ---- phase 2: accumulate
    float acc0 = 0.0f, acc1 = 0.0f, acc2 = 0.0f, acc3 = 0.0f;
    int d0 = 0, d1 = 0, d2 = 0, d3 = 0;
    float s0 = 0.0f, s1 = 0.0f, s2 = 0.0f;
    if (l < 63) {
        int off0, off1, off2, off3;
        const int r = 4 * l;
        #define DECOMP(c, OFF, DD) { int rc = r + (c); int ko = (rc >= 126) ? 1 : 0; \
            int rr = rc - 126 * ko; int f = rr / 3; (DD) = rr - 3 * f; (OFF) = ko * NF + f; }
        DECOMP(0, off0, d0) DECOMP(1, off1, d1) DECOMP(2, off2, d2) DECOMP(3, off3, d3)
        #undef DECOMP

        #pragma unroll
        for (int i = 0; i < 13; ++i) {
            int p = start + i;
            if (p > 49) p = 49;          // dummy iter reads valid LDS, v[i]==0
            const float* base = dE_s + 84 * p;
            acc0 += v[i].x * base[off0];
            acc1 += v[i].y * base[off1];
            acc2 += v[i].z * base[off2];
            acc3 += v[i].w * base[off3];
        }

        // merge 4 per-lane accumulators into 3 components (branchless)
        s0 = (d0 == 0 ? acc0 : 0.0f) + (d1 == 0 ? acc1 : 0.0f) +
             (d2 == 0 ? acc2 : 0.0f) + (d3 == 0 ? acc3 : 0.0f);
        s1 = (d0 == 1 ? acc0 : 0.0f) + (d1 == 1 ? acc1 : 0.0f) +
             (d2 == 1 ? acc2 : 0.0f) + (d3 == 1 ? acc3 : 0.0f);
        s2 = (d0 == 2 ? acc0 : 0.0f) + (d1 == 2 ? acc1 : 0.0f) +
             (d2 == 2 ? acc2 : 0.0f) + (d3 == 2 ? acc3 : 0.0f);
    }

    // ---- phase 3: wave-level butterfly reduce (lane 63 contributes zeros)
    #pragma unroll
    for (int m = 32; m > 0; m >>= 1) {
        s0 += __shfl_xor(s0, m);
        s1 += __shfl_xor(s1, m);
        s2 += __shfl_xor(s2, m);
    }
    if (l == 0) { part[w][0] = s0; part[w][1] = s1; part[w][2] = s2; }
    __syncthreads();
    if (tid < 3)
        outForce[(size_t)bn * 3 + tid] =
            part[0][tid] + part[1][tid] + part[2][tid] + part[3][tid];
}

extern "C" void kernel_launch(void* const* d_in, const int* in_sizes, int n_in,
                              void* d_out, int out_size, void* d_ws, size_t ws_size,
                              hipStream_t stream) {
    const float* image    = (const float*)d_in[0];
    const float* dfeat    = (const float*)d_in[1];
    const int*   neighbor = (const int*)d_in[2];
    const float* W0_t0 = (const float*)d_in[3];
    const float* b0_t0 = (const float*)d_in[4];
    const float* W1_t0 = (const float*)d_in[5];
    const float* b1_t0 = (const float*)d_in[6];
    const float* W2_t0 = (const float*)d_in[7];
    const float* b2_t0 = (const float*)d_in[8];
    const float* W0_t1 = (const float*)d_in[9];
    const float* b0_t1 = (const float*)d_in[10];
    const float* W1_t1 = (const float*)d_in[11];
    const float* b1_t1 = (const float*)d_in[12];
    const float* W2_t1 = (const float*)d_in[13];
    const float* b2_t1 = (const float*)d_in[14];

    float* outEtot  = (float*)d_out;          // 32
    float* outEi    = outEtot + BB;           // 32*256 = 8192
    float* outForce = outEi + BB * NATOM;     // 32*256*3 = 24576
    float* dEp      = (float*)d_ws;           // 32*257*42 floats = 1.38 MB

    // Etot is accumulated with atomics -> zero its region every call
    hipMemsetAsync(d_out, 0, BB * sizeof(float), stream);

    mlp_fwd_bwd<<<64, 128, 0, stream>>>(
        image,
        W0_t0, b0_t0, W1_t0, b1_t0, W2_t0, b2_t0,
        W0_t1, b0_t1, W1_t1, b1_t1, W2_t1, b2_t1,
        outEtot, outEi, dEp);

    force_kernel<<<BB * NATOM, 256, 0, stream>>>(dfeat, neighbor, dEp, outForce);
}

// Round 3
// 621.502 us; speedup vs baseline: 1.0257x; 1.0062x over previous
//
#include <hip/hip_runtime.h>
#include <cstdint>

#define BB 32
#define NATOM 256
#define NN 100
#define NF 42
#define HH 50
#define PADROWS 257                    // 1 + NATOM
#define DE_STRIDE (PADROWS * NF)       // 10794 floats per batch

// fast tanh: 1 - 2/(e^{2x}+1).  Saturates correctly at +/-1 (e->0 or inf).
__device__ __forceinline__ float fast_tanh(float x) {
    const float e = __expf(2.0f * x);
    return 1.0f - 2.0f / (e + 1.0f);
}

// ---------------------------------------------------------------------------
// Kernel 1: per-atom MLP forward (Ei, Etot partials) + input gradient dE/dx.
// grid = 128 blocks x 64 threads (1 wave/block -> 128 CUs busy).
// blk = b*4 + q ; q in 0..3 ; atoms q*64..q*64+63 ; half = q>>1 (param set).
// Weights staged in LDS; inner-loop reads are wave-uniform -> broadcast.
// Etot partials go to ws (finalized by force_kernel) -> no memset dispatch.
// ---------------------------------------------------------------------------
__global__ __launch_bounds__(64) void mlp_fwd_bwd(
    const float* __restrict__ image,
    const float* __restrict__ W0a, const float* __restrict__ b0a,
    const float* __restrict__ W1a, const float* __restrict__ b1a,
    const float* __restrict__ W2a, const float* __restrict__ b2a,
    const float* __restrict__ W0b, const float* __restrict__ b0b,
    const float* __restrict__ W1b, const float* __restrict__ b1b,
    const float* __restrict__ W2b, const float* __restrict__ b2b,
    float* __restrict__ outEi,     // [32*256]
    float* __restrict__ dEp,       // [32 * 257 * 42] (row 0 per batch = zeros)
    float* __restrict__ Epart)     // [32*4] Etot partials
{
    __shared__ float W0s[NF * HH];
    __shared__ float W1s[HH * HH];
    __shared__ float W2s[HH], b0s[HH], b1s[HH];
    __shared__ float b2s;

    const int blk = blockIdx.x;
    const int b   = blk >> 2;
    const int q   = blk & 3;
    const int half = q >> 1;
    const int tid = threadIdx.x;

    const float* W0 = half ? W0b : W0a;
    const float* b0 = half ? b0b : b0a;
    const float* W1 = half ? W1b : W1a;
    const float* b1 = half ? b1b : b1a;
    const float* W2 = half ? W2b : W2a;
    const float* b2 = half ? b2b : b2a;

    for (int i = tid; i < NF * HH; i += 64) W0s[i] = W0[i];
    for (int i = tid; i < HH * HH; i += 64) W1s[i] = W1[i];
    if (tid < HH) { W2s[tid] = W2[tid]; b0s[tid] = b0[tid]; b1s[tid] = b1[tid]; }
    if (tid == 0) b2s = b2[0];

    // zero pad-row (dE_pad[b][0][:]) once per batch
    if (q == 0 && tid < NF) dEp[(size_t)b * DE_STRIDE + tid] = 0.0f;
    __syncthreads();

    const int n = q * 64 + tid;              // atom within batch
    const int g = b * NATOM + n;             // global atom

    float x[NF];
    {
        // row is 168 B (8-aligned) -> 21 aligned float2 loads
        const float2* xp = (const float2*)(image + (size_t)g * NF);
        #pragma unroll
        for (int f = 0; f < NF / 2; ++f) {
            const float2 v = xp[f];
            x[2 * f] = v.x;
            x[2 * f + 1] = v.y;
        }
    }

    float h0[HH], h1[HH];

    // layer 0: h0 = tanh(x @ W0 + b0), 2-way j-unroll for ILP
    for (int j = 0; j < HH; j += 2) {
        float s0 = b0s[j], s1 = b0s[j + 1];
        #pragma unroll
        for (int f = 0; f < NF; ++f) {
            const float xf = x[f];
            s0 += xf * W0s[f * HH + j];
            s1 += xf * W0s[f * HH + j + 1];
        }
        h0[j] = fast_tanh(s0);
        h0[j + 1] = fast_tanh(s1);
    }

    // layer 1: h1 = tanh(h0 @ W1 + b1)
    for (int j = 0; j < HH; j += 2) {
        float s0 = b1s[j], s1 = b1s[j + 1];
        #pragma unroll
        for (int i = 0; i < HH; ++i) {
            const float hi = h0[i];
            s0 += hi * W1s[i * HH + j];
            s1 += hi * W1s[i * HH + j + 1];
        }
        h1[j] = fast_tanh(s0);
        h1[j + 1] = fast_tanh(s1);
    }

    // output: Ei = h1 @ W2 + b2
    float Ei0 = 0.0f, Ei1 = 0.0f;
    for (int j = 0; j < HH; j += 2) {
        Ei0 += h1[j] * W2s[j];
        Ei1 += h1[j + 1] * W2s[j + 1];
    }
    const float Ei = Ei0 + Ei1 + b2s;
    outEi[g] = Ei;

    // Etot partial: wave butterfly reduce, lane 0 stores
    float s = Ei;
    #pragma unroll
    for (int m = 32; m > 0; m >>= 1) s += __shfl_xor(s, m);
    if (tid == 0) Epart[b * 4 + q] = s;

    // ---- backward: dEi/dx = W0 diag(1-h0^2) W1 diag(1-h1^2) W2 ----
    #pragma unroll
    for (int j = 0; j < HH; ++j) {
        const float t = h1[j];
        h1[j] = W2s[j] * (1.0f - t * t);
    }
    for (int i = 0; i < HH; i += 2) {
        float s0 = 0.0f, s1 = 0.0f;
        #pragma unroll
        for (int j = 0; j < HH; ++j) {
            const float gj = h1[j];
            s0 += gj * W1s[i * HH + j];
            s1 += gj * W1s[(i + 1) * HH + j];
        }
        const float t0 = h0[i], t1 = h0[i + 1];
        h0[i] = s0 * (1.0f - t0 * t0);
        h0[i + 1] = s1 * (1.0f - t1 * t1);
    }
    // dx = W0 @ g0   (168-B rows, 8-aligned -> float2 stores)
    float2* dxp = (float2*)(dEp + (size_t)b * DE_STRIDE + (size_t)(1 + n) * NF);
    for (int f = 0; f < NF; f += 2) {
        float s0 = 0.0f, s1 = 0.0f;
        #pragma unroll
        for (int i = 0; i < HH; ++i) {
            const float gi = h0[i];
            s0 += gi * W0s[f * HH + i];
            s1 += gi * W0s[(f + 1) * HH + i];
        }
        dxp[f >> 1] = make_float2(s0, s1);
    }
}

// ---------------------------------------------------------------------------
// Kernel 2: Force[b,n,d] = sum_{k,f} dE_pad[b, nbr[b,n,k], f] * dfeat[b,n,k,f,d]
// One block (256 thr = 4 waves) per (b,n). dfeat loads issued first (in
// flight across the gather phase); contiguous per-wave chunk-pair ranges keep
// each lane's (k_off,f,d) decomposition loop-invariant; shfl_xor reduction.
// n==0 blocks also finalize Etot[b] from the MLP partials.
// ---------------------------------------------------------------------------
__global__ __launch_bounds__(256) void force_kernel(
    const float* __restrict__ dfeat,     // [32*256*100*42*3]
    const int* __restrict__ neighbor,    // [32*256*100]
    const float* __restrict__ dEp,       // [32 * 257 * 42]
    const float* __restrict__ Epart,     // [32*4]
    float* __restrict__ outEtot,         // [32]
    float* __restrict__ outForce)        // [32*256*3]
{
    __shared__ int   nbr_s[NN];
    __shared__ float dE_s[NN * NF];      // 16.8 KB
    __shared__ float part[4][3];

    const int bn  = blockIdx.x;          // b*256 + n
    const int b   = bn >> 8;
    const int tid = threadIdx.x;
    const int w   = tid >> 6;            // wave 0..3
    const int l   = tid & 63;            // lane

    // wave w owns chunk-pairs [start, start+cnt): 13,13,12,12
    const int start = (w < 2) ? 13 * w : 26 + 12 * (w - 2);

    // ---- phase 0: issue all dfeat loads (63 active lanes x up to 13 float4)
    float4 v[13];
    const float4* df4 = (const float4*)dfeat + (size_t)bn * 3150;
    if (l < 63) {
        #pragma unroll
        for (int i = 0; i < 13; ++i) {
            int p = start + i;
            if (p > 49) p = 49;          // clamp (w>=2, i==12): valid addr, zeroed below
            v[i] = df4[p * 63 + l];
        }
        if (w >= 2) v[12] = make_float4(0.0f, 0.0f, 0.0f, 0.0f);
    }

    // ---- phase 1: neighbors + dE gather into LDS (overlaps dfeat latency)
    if (tid < NN) nbr_s[tid] = neighbor[(size_t)bn * NN + tid];
    __syncthreads();
    {
        // rows are 42 floats (8-aligned) -> gather as float2
        const float2* dEb2 = (const float2*)(dEp + (size_t)b * DE_STRIDE);
        float2* dEs2 = (float2*)dE_s;
        for (int q = tid; q < NN * (NF / 2); q += 256) {
            const int k = q / (NF / 2);
            const int f2 = q - k * (NF / 2);
            dEs2[q] = dEb2[nbr_s[k] * (NF / 2) + f2];
        }
    }
    __syncthreads();

    // ---- phase 2: accumulate
    int d0 = 0, d1 = 0, d2 = 0, d3 = 0;
    float s0 = 0.0f, s1 = 0.0f, s2 = 0.0f;
    if (l < 63) {
        float acc0 = 0.0f, acc1 = 0.0f, acc2 = 0.0f, acc3 = 0.0f;
        int off0, off1, off2, off3;
        const int r = 4 * l;
        #define DECOMP(c, OFF, DD) { int rc = r + (c); int ko = (rc >= 126) ? 1 : 0; \
            int rr = rc - 126 * ko; int f = rr / 3; (DD) = rr - 3 * f; (OFF) = ko * NF + f; }
        DECOMP(0, off0, d0) DECOMP(1, off1, d1) DECOMP(2, off2, d2) DECOMP(3, off3, d3)
        #undef DECOMP

        #pragma unroll
        for (int i = 0; i < 13; ++i) {
            int p = start + i;
            if (p > 49) p = 49;          // dummy iter reads valid LDS, v[i]==0
            const float* base = dE_s + 84 * p;
            acc0 += v[i].x * base[off0];
            acc1 += v[i].y * base[off1];
            acc2 += v[i].z * base[off2];
            acc3 += v[i].w * base[off3];
        }

        s0 = (d0 == 0 ? acc0 : 0.0f) + (d1 == 0 ? acc1 : 0.0f) +
             (d2 == 0 ? acc2 : 0.0f) + (d3 == 0 ? acc3 : 0.0f);
        s1 = (d0 == 1 ? acc0 : 0.0f) + (d1 == 1 ? acc1 : 0.0f) +
             (d2 == 1 ? acc2 : 0.0f) + (d3 == 1 ? acc3 : 0.0f);
        s2 = (d0 == 2 ? acc0 : 0.0f) + (d1 == 2 ? acc1 : 0.0f) +
             (d2 == 2 ? acc2 : 0.0f) + (d3 == 2 ? acc3 : 0.0f);
    }

    // ---- phase 3: wave butterfly reduce (lane 63 contributes zeros)
    #pragma unroll
    for (int m = 32; m > 0; m >>= 1) {
        s0 += __shfl_xor(s0, m);
        s1 += __shfl_xor(s1, m);
        s2 += __shfl_xor(s2, m);
    }
    if (l == 0) { part[w][0] = s0; part[w][1] = s1; part[w][2] = s2; }
    __syncthreads();
    if (tid < 3)
        outForce[(size_t)bn * 3 + tid] =
            part[0][tid] + part[1][tid] + part[2][tid] + part[3][tid];

    // finalize Etot (one block per batch; partials ready since mlp completed)
    if ((bn & 255) == 0 && tid == 3)
        outEtot[b] = Epart[b * 4] + Epart[b * 4 + 1] +
                     Epart[b * 4 + 2] + Epart[b * 4 + 3];
}

extern "C" void kernel_launch(void* const* d_in, const int* in_sizes, int n_in,
                              void* d_out, int out_size, void* d_ws, size_t ws_size,
                              hipStream_t stream) {
    const float* image    = (const float*)d_in[0];
    const float* dfeat    = (const float*)d_in[1];
    const int*   neighbor = (const int*)d_in[2];
    const float* W0_t0 = (const float*)d_in[3];
    const float* b0_t0 = (const float*)d_in[4];
    const float* W1_t0 = (const float*)d_in[5];
    const float* b1_t0 = (const float*)d_in[6];
    const float* W2_t0 = (const float*)d_in[7];
    const float* b2_t0 = (const float*)d_in[8];
    const float* W0_t1 = (const float*)d_in[9];
    const float* b0_t1 = (const float*)d_in[10];
    const float* W1_t1 = (const float*)d_in[11];
    const float* b1_t1 = (const float*)d_in[12];
    const float* W2_t1 = (const float*)d_in[13];
    const float* b2_t1 = (const float*)d_in[14];

    float* outEtot  = (float*)d_out;          // 32
    float* outEi    = outEtot + BB;           // 32*256 = 8192
    float* outForce = outEi + BB * NATOM;     // 32*256*3 = 24576
    float* dEp      = (float*)d_ws;           // 32*257*42 floats = 1.38 MB
    float* Epart    = dEp + BB * DE_STRIDE;   // 32*4 floats

    mlp_fwd_bwd<<<128, 64, 0, stream>>>(
        image,
        W0_t0, b0_t0, W1_t0, b1_t0, W2_t0, b2_t0,
        W0_t1, b0_t1, W1_t1, b1_t1, W2_t1, b2_t1,
        outEi, dEp, Epart);

    force_kernel<<<BB * NATOM, 256, 0, stream>>>(dfeat, neighbor, dEp, Epart,
                                                 outEtot, outForce);
}